// Round 1
// baseline (945.797 us; speedup 1.0000x reference)
//
#include <hip/hip_runtime.h>
#include <hip/hip_bf16.h>

#define N_NODES 100000
#define N_RELS  4
#define N_EDGES 250000
#define D       128
#define TM      32

// ---------------------------------------------------------------------------
// Scatter: msg[dst] += x[src], deg[dst] += 1.  128 threads per edge (one
// feature each), coalesced 512B row gather, f32 global atomics for scatter.
// ---------------------------------------------------------------------------
__global__ __launch_bounds__(256) void scatter_kernel(
    const float* __restrict__ x,
    const int* __restrict__ src,
    const int* __restrict__ dst,
    float* __restrict__ msg,
    float* __restrict__ deg,
    int n_edges)
{
    int tid  = blockIdx.x * 256 + threadIdx.x;
    int edge = tid >> 7;          // 128 threads per edge
    int lane = tid & 127;
    if (edge >= n_edges) return;
    int s = src[edge];
    int d = dst[edge];
    float v = x[s * D + lane];
    atomicAdd(&msg[d * D + lane], v);
    if (lane == 0) atomicAdd(&deg[d], 1.0f);
}

// ---------------------------------------------------------------------------
// Tiled fp32 GEMM + fused epilogue.
//   mode 0: out  = relu(in_norm @ W + b) * 0.25        (first relation)
//   mode 1: out += relu(in_norm @ W + b) * 0.25        (relations 1..3)
//   mode 2: out  = relu(silu(out) + in @ W + b)        (self-loop finale)
// Block: 256 threads, tile 32 rows x 128 cols, 4x4 register blocking.
// LDS: W staged in two 64-row chunks (32 KB) + input tile (16.9 KB) -> ~51 KB
// -> 3 blocks/CU.
// ---------------------------------------------------------------------------
__global__ __launch_bounds__(256) void gemm_phase(
    const float* __restrict__ in,    // [N, D]
    const float* __restrict__ deg,   // [N] or nullptr
    const float* __restrict__ W,     // [D, D] (k-major rows)
    const float* __restrict__ bias,  // [D]
    float* __restrict__ out,         // [N, D]
    int mode)
{
    __shared__ float sW[64 * D];           // one 64-row K-chunk of W
    __shared__ float sIn[TM * (D + 4)];    // padded stride 132

    const int tid  = threadIdx.x;
    const int row0 = blockIdx.x * TM;

    // ---- load input tile (TM x D), normalized by degree if requested ----
    #pragma unroll
    for (int j = 0; j < 4; ++j) {
        int id = tid + j * 256;            // float4 id, 0..1023
        int r  = id >> 5;                  // tile row
        int k0 = (id & 31) * 4;            // col within row
        float4 v = *reinterpret_cast<const float4*>(&in[(row0 + r) * D + k0]);
        float scale = 1.0f;
        if (deg) scale = 1.0f / fmaxf(deg[row0 + r], 1.0f);
        float* p = &sIn[r * (D + 4) + k0];
        p[0] = v.x * scale; p[1] = v.y * scale;
        p[2] = v.z * scale; p[3] = v.w * scale;
    }

    const int tc = tid & 31;   // col group: cols tc*4 .. tc*4+3
    const int tr = tid >> 5;   // row group: rows tr*4 .. tr*4+3

    float acc[4][4];
    #pragma unroll
    for (int i = 0; i < 4; ++i)
        #pragma unroll
        for (int j = 0; j < 4; ++j) acc[i][j] = 0.0f;

    for (int kc = 0; kc < 2; ++kc) {
        __syncthreads();                   // protect sW reuse / sIn readiness
        // stage 64x128 chunk of W (2048 float4, 8 per thread), coalesced
        #pragma unroll
        for (int j = 0; j < 8; ++j) {
            int id = tid + j * 256;
            reinterpret_cast<float4*>(sW)[id] =
                reinterpret_cast<const float4*>(W + kc * 64 * D)[id];
        }
        __syncthreads();

        #pragma unroll 8
        for (int k = 0; k < 64; ++k) {
            float4 w4 = *reinterpret_cast<const float4*>(&sW[k * D + tc * 4]);
            float wv[4] = { w4.x, w4.y, w4.z, w4.w };
            float iv[4];
            #pragma unroll
            for (int i = 0; i < 4; ++i)
                iv[i] = sIn[(tr * 4 + i) * (D + 4) + (kc * 64 + k)];
            #pragma unroll
            for (int i = 0; i < 4; ++i)
                #pragma unroll
                for (int j = 0; j < 4; ++j)
                    acc[i][j] += iv[i] * wv[j];
        }
    }

    // ---- epilogue ----
    #pragma unroll
    for (int i = 0; i < 4; ++i) {
        int row  = row0 + tr * 4 + i;
        float* op = &out[row * D + tc * 4];
        #pragma unroll
        for (int j = 0; j < 4; ++j) {
            float h = acc[i][j] + bias[tc * 4 + j];
            if (mode == 0) {
                op[j] = fmaxf(h, 0.0f) * 0.25f;
            } else if (mode == 1) {
                op[j] += fmaxf(h, 0.0f) * 0.25f;
            } else {
                float t = op[j];                     // mean of relu'd rels
                float s = t / (1.0f + __expf(-t));   // silu (t >= 0, safe)
                op[j] = fmaxf(s + h, 0.0f);
            }
        }
    }
}

// ---------------------------------------------------------------------------
extern "C" void kernel_launch(void* const* d_in, const int* in_sizes, int n_in,
                              void* d_out, int out_size, void* d_ws, size_t ws_size,
                              hipStream_t stream) {
    const float* x         = (const float*)d_in[0];
    const float* weight    = (const float*)d_in[1];
    const float* conv_bias = (const float*)d_in[2];
    const float* loop_w    = (const float*)d_in[3];
    const float* node_bias = (const float*)d_in[4];
    const int*   src       = (const int*)d_in[5];
    const int*   dst       = (const int*)d_in[6];
    float* out = (float*)d_out;

    float* msg = (float*)d_ws;
    float* deg = (float*)((char*)d_ws + (size_t)N_NODES * D * sizeof(float));
    size_t zero_bytes = (size_t)N_NODES * D * sizeof(float)
                      + (size_t)N_NODES * sizeof(float);

    dim3 sblk(256);
    dim3 sgrd((N_EDGES * 128) / 256);      // 125000 blocks
    dim3 gblk(256);
    dim3 ggrd(N_NODES / TM);               // 3125 blocks (100000 % 32 == 0)

    for (int r = 0; r < N_RELS; ++r) {
        hipMemsetAsync(d_ws, 0, zero_bytes, stream);
        scatter_kernel<<<sgrd, sblk, 0, stream>>>(
            x, src + (size_t)r * N_EDGES, dst + (size_t)r * N_EDGES,
            msg, deg, N_EDGES);
        gemm_phase<<<ggrd, gblk, 0, stream>>>(
            msg, deg, weight + (size_t)r * D * D, conv_bias + (size_t)r * D,
            out, r == 0 ? 0 : 1);
    }
    gemm_phase<<<ggrd, gblk, 0, stream>>>(x, nullptr, loop_w, node_bias, out, 2);
}

// Round 2
// 487.686 us; speedup vs baseline: 1.9394x; 1.9394x over previous
//
#include <hip/hip_runtime.h>
#include <hip/hip_bf16.h>

#define N_NODES 100000
#define N_RELS  4
#define N_EDGES 250000
#define TOTAL_E (N_RELS * N_EDGES)
#define NR      (N_RELS * N_NODES)   // 400000 (deg/off entries)
#define D       128
#define TM      32

// ---------------------------------------------------------------------------
// CSR build: histogram -> 2-level exclusive scan -> fill (int atomics only).
// Global scan over concatenated [4 x 100K] degrees gives global positions in
// a single 1M-entry sorted_src buffer (relation bases are exactly r*250000).
// ---------------------------------------------------------------------------
__global__ __launch_bounds__(256) void hist_kernel(
    const int* __restrict__ dst, int* __restrict__ deg, int total)
{
    int i = blockIdx.x * 256 + threadIdx.x;
    if (i >= total) return;
    int rel = i / N_EDGES;
    atomicAdd(&deg[rel * N_NODES + dst[i]], 1);
}

__global__ __launch_bounds__(256) void scan1_kernel(
    const int* __restrict__ in, int* __restrict__ out,
    int* __restrict__ aux, int n)
{
    __shared__ int s[256];
    int t = threadIdx.x;
    int base = blockIdx.x * 1024 + t * 4;
    int v[4];
    int sum = 0;
    #pragma unroll
    for (int j = 0; j < 4; ++j) {
        v[j] = (base + j < n) ? in[base + j] : 0;
        sum += v[j];
    }
    s[t] = sum;
    for (int off = 1; off < 256; off <<= 1) {
        __syncthreads();
        int u = (t >= off) ? s[t - off] : 0;
        __syncthreads();
        s[t] += u;
    }
    __syncthreads();
    int excl = (t > 0) ? s[t - 1] : 0;
    #pragma unroll
    for (int j = 0; j < 4; ++j) {
        if (base + j < n) out[base + j] = excl;
        excl += v[j];
    }
    if (t == 255) aux[blockIdx.x] = s[255];
}

__global__ __launch_bounds__(512) void scan2_kernel(int* __restrict__ aux, int n)
{
    __shared__ int s[512];
    int t = threadIdx.x;
    s[t] = (t < n) ? aux[t] : 0;
    for (int off = 1; off < 512; off <<= 1) {
        __syncthreads();
        int u = (t >= off) ? s[t - off] : 0;
        __syncthreads();
        s[t] += u;
    }
    __syncthreads();
    int excl = (t > 0) ? s[t - 1] : 0;
    if (t < n) aux[t] = excl;
}

__global__ __launch_bounds__(256) void addoff_kernel(
    int* __restrict__ off, int* __restrict__ cursor,
    const int* __restrict__ aux, int n)
{
    int i = blockIdx.x * 256 + threadIdx.x;
    if (i >= n) return;
    int v = off[i] + aux[i >> 10];
    off[i] = v;
    cursor[i] = v;
}

__global__ __launch_bounds__(256) void fill_kernel(
    const int* __restrict__ dst, const int* __restrict__ src,
    int* __restrict__ cursor, int* __restrict__ sorted_src, int total)
{
    int i = blockIdx.x * 256 + threadIdx.x;
    if (i >= total) return;
    int rel = i / N_EDGES;
    int pos = atomicAdd(&cursor[rel * N_NODES + dst[i]], 1);
    sorted_src[pos] = src[i];
}

// ---------------------------------------------------------------------------
// Fused: per 32-row tile, 5 phases (4 relations via CSR gather + self-loop),
// accumulate 0.25*relu(tile@W_r+b_r) in registers, then
// out = relu(silu(mean) + x@loop_w + node_bias). One output write total.
// ---------------------------------------------------------------------------
__global__ __launch_bounds__(256) void fused_gemm(
    const float* __restrict__ x,
    const float* __restrict__ weight,     // [4,128,128]
    const float* __restrict__ conv_bias,  // [4,128]
    const float* __restrict__ loop_w,     // [128,128]
    const float* __restrict__ node_bias,  // [128]
    const int* __restrict__ deg,          // [4*N]
    const int* __restrict__ off,          // [4*N]
    const int* __restrict__ sorted_src,   // [1M]
    float* __restrict__ out)
{
    __shared__ float sW[64 * D];
    __shared__ float sIn[TM * (D + 4)];

    const int tid  = threadIdx.x;
    const int row0 = blockIdx.x * TM;
    const int tc = tid & 31;   // col group (cols tc*4..tc*4+3)
    const int tr = tid >> 5;   // row group (rows tr*4..tr*4+3)

    float acc_mean[4][4];
    float acc_self[4][4];
    #pragma unroll
    for (int i = 0; i < 4; ++i)
        #pragma unroll
        for (int j = 0; j < 4; ++j) acc_mean[i][j] = 0.0f;

    for (int phase = 0; phase < 5; ++phase) {
        __syncthreads();   // previous phase fully done before sIn overwrite

        // ---- stage input tile into sIn ----
        if (phase < 4) {
            // CSR gather: 8 threads per row, 16 cols per thread
            int r = tid >> 3;
            int c = tid & 7;
            int node = row0 + r;
            int dgi = deg[phase * N_NODES + node];
            int beg = off[phase * N_NODES + node];
            float a[16];
            #pragma unroll
            for (int j = 0; j < 16; ++j) a[j] = 0.0f;
            for (int e = 0; e < dgi; ++e) {
                const float* xp = x + (size_t)sorted_src[beg + e] * D + c * 16;
                float4 v0 = *reinterpret_cast<const float4*>(xp);
                float4 v1 = *reinterpret_cast<const float4*>(xp + 4);
                float4 v2 = *reinterpret_cast<const float4*>(xp + 8);
                float4 v3 = *reinterpret_cast<const float4*>(xp + 12);
                a[0] += v0.x; a[1] += v0.y; a[2]  += v0.z; a[3]  += v0.w;
                a[4] += v1.x; a[5] += v1.y; a[6]  += v1.z; a[7]  += v1.w;
                a[8] += v2.x; a[9] += v2.y; a[10] += v2.z; a[11] += v2.w;
                a[12]+= v3.x; a[13]+= v3.y; a[14] += v3.z; a[15] += v3.w;
            }
            float scale = 1.0f / fmaxf((float)dgi, 1.0f);
            float* p = &sIn[r * (D + 4) + c * 16];
            #pragma unroll
            for (int j = 0; j < 16; ++j) p[j] = a[j] * scale;
        } else {
            // self-loop: plain x tile
            #pragma unroll
            for (int j = 0; j < 4; ++j) {
                int id = tid + j * 256;
                int r  = id >> 5;
                int k0 = (id & 31) * 4;
                float4 v = *reinterpret_cast<const float4*>(&x[(row0 + r) * D + k0]);
                float* p = &sIn[r * (D + 4) + k0];
                p[0] = v.x; p[1] = v.y; p[2] = v.z; p[3] = v.w;
            }
        }

        const float* Wp = (phase < 4) ? (weight + (size_t)phase * D * D) : loop_w;

        float acc[4][4];
        #pragma unroll
        for (int i = 0; i < 4; ++i)
            #pragma unroll
            for (int j = 0; j < 4; ++j) acc[i][j] = 0.0f;

        for (int kc = 0; kc < 2; ++kc) {
            __syncthreads();   // sIn writes visible; sW safe to overwrite
            #pragma unroll
            for (int j = 0; j < 8; ++j) {
                int id = tid + j * 256;
                reinterpret_cast<float4*>(sW)[id] =
                    reinterpret_cast<const float4*>(Wp + kc * 64 * D)[id];
            }
            __syncthreads();

            #pragma unroll 8
            for (int k = 0; k < 64; ++k) {
                float4 w4 = *reinterpret_cast<const float4*>(&sW[k * D + tc * 4]);
                float wv[4] = { w4.x, w4.y, w4.z, w4.w };
                float iv[4];
                #pragma unroll
                for (int i = 0; i < 4; ++i)
                    iv[i] = sIn[(tr * 4 + i) * (D + 4) + (kc * 64 + k)];
                #pragma unroll
                for (int i = 0; i < 4; ++i)
                    #pragma unroll
                    for (int j = 0; j < 4; ++j)
                        acc[i][j] += iv[i] * wv[j];
            }
        }

        // ---- per-phase epilogue into registers ----
        if (phase < 4) {
            const float* b = conv_bias + phase * D + tc * 4;
            #pragma unroll
            for (int i = 0; i < 4; ++i)
                #pragma unroll
                for (int j = 0; j < 4; ++j)
                    acc_mean[i][j] += 0.25f * fmaxf(acc[i][j] + b[j], 0.0f);
        } else {
            const float* nb = node_bias + tc * 4;
            #pragma unroll
            for (int i = 0; i < 4; ++i)
                #pragma unroll
                for (int j = 0; j < 4; ++j)
                    acc_self[i][j] = acc[i][j] + nb[j];
        }
    }

    // ---- final epilogue: silu(mean) + self + relu, single write ----
    #pragma unroll
    for (int i = 0; i < 4; ++i) {
        float4 o;
        float* po = reinterpret_cast<float*>(&o);
        #pragma unroll
        for (int j = 0; j < 4; ++j) {
            float m = acc_mean[i][j];                 // >= 0
            float s = m / (1.0f + __expf(-m));        // silu
            po[j] = fmaxf(s + acc_self[i][j], 0.0f);
        }
        *reinterpret_cast<float4*>(&out[(size_t)(row0 + tr * 4 + i) * D + tc * 4]) = o;
    }
}

// ---------------------------------------------------------------------------
extern "C" void kernel_launch(void* const* d_in, const int* in_sizes, int n_in,
                              void* d_out, int out_size, void* d_ws, size_t ws_size,
                              hipStream_t stream) {
    const float* x         = (const float*)d_in[0];
    const float* weight    = (const float*)d_in[1];
    const float* conv_bias = (const float*)d_in[2];
    const float* loop_w    = (const float*)d_in[3];
    const float* node_bias = (const float*)d_in[4];
    const int*   src       = (const int*)d_in[5];  // [4, 250K] flat
    const int*   dst       = (const int*)d_in[6];
    float* out = (float*)d_out;

    // ws layout
    char* w = (char*)d_ws;
    int* deg        = (int*)(w);                         // 400000
    int* off        = (int*)(w + 1600000);               // 400000
    int* cursor     = (int*)(w + 3200000);               // 400000
    int* aux        = (int*)(w + 4800000);               // 512
    int* sorted_src = (int*)(w + 4802048);               // 1M

    const int SCAN_BLKS = (NR + 1023) / 1024;            // 391

    hipMemsetAsync(deg, 0, NR * sizeof(int), stream);
    hist_kernel<<<(TOTAL_E + 255) / 256, 256, 0, stream>>>(dst, deg, TOTAL_E);
    scan1_kernel<<<SCAN_BLKS, 256, 0, stream>>>(deg, off, aux, NR);
    scan2_kernel<<<1, 512, 0, stream>>>(aux, SCAN_BLKS);
    addoff_kernel<<<(NR + 255) / 256, 256, 0, stream>>>(off, cursor, aux, NR);
    fill_kernel<<<(TOTAL_E + 255) / 256, 256, 0, stream>>>(dst, src, cursor,
                                                           sorted_src, TOTAL_E);
    fused_gemm<<<N_NODES / TM, 256, 0, stream>>>(
        x, weight, conv_bias, loop_w, node_bias, deg, off, sorted_src, out);
}

// Round 3
// 355.360 us; speedup vs baseline: 2.6615x; 1.3724x over previous
//
#include <hip/hip_runtime.h>
#include <hip/hip_bf16.h>

#define N_NODES 100000
#define N_RELS  4
#define N_EDGES 250000
#define TOTAL_E (N_RELS * N_EDGES)
#define NR      (N_RELS * N_NODES)
#define D       128

typedef __attribute__((ext_vector_type(8))) short bf16x8;
typedef __attribute__((ext_vector_type(4))) float f32x4;

__device__ __forceinline__ float b2f(short u) {
    unsigned int x = ((unsigned int)(unsigned short)u) << 16;
    return __builtin_bit_cast(float, x);
}
__device__ __forceinline__ unsigned short f2b(float f) {
    unsigned int u = __builtin_bit_cast(unsigned int, f);
    return (unsigned short)((u + 0x7fffu + ((u >> 16) & 1u)) >> 16);  // RNE
}

// ---------------------------------------------------------------------------
// CSR build (unchanged from R2)
// ---------------------------------------------------------------------------
__global__ __launch_bounds__(256) void hist_kernel(
    const int* __restrict__ dst, int* __restrict__ deg, int total)
{
    int i = blockIdx.x * 256 + threadIdx.x;
    if (i >= total) return;
    int rel = i / N_EDGES;
    atomicAdd(&deg[rel * N_NODES + dst[i]], 1);
}

__global__ __launch_bounds__(256) void scan1_kernel(
    const int* __restrict__ in, int* __restrict__ out,
    int* __restrict__ aux, int n)
{
    __shared__ int s[256];
    int t = threadIdx.x;
    int base = blockIdx.x * 1024 + t * 4;
    int v[4];
    int sum = 0;
    #pragma unroll
    for (int j = 0; j < 4; ++j) {
        v[j] = (base + j < n) ? in[base + j] : 0;
        sum += v[j];
    }
    s[t] = sum;
    for (int off = 1; off < 256; off <<= 1) {
        __syncthreads();
        int u = (t >= off) ? s[t - off] : 0;
        __syncthreads();
        s[t] += u;
    }
    __syncthreads();
    int excl = (t > 0) ? s[t - 1] : 0;
    #pragma unroll
    for (int j = 0; j < 4; ++j) {
        if (base + j < n) out[base + j] = excl;
        excl += v[j];
    }
    if (t == 255) aux[blockIdx.x] = s[255];
}

__global__ __launch_bounds__(512) void scan2_kernel(int* __restrict__ aux, int n)
{
    __shared__ int s[512];
    int t = threadIdx.x;
    s[t] = (t < n) ? aux[t] : 0;
    for (int off = 1; off < 512; off <<= 1) {
        __syncthreads();
        int u = (t >= off) ? s[t - off] : 0;
        __syncthreads();
        s[t] += u;
    }
    __syncthreads();
    int excl = (t > 0) ? s[t - 1] : 0;
    if (t < n) aux[t] = excl;
}

__global__ __launch_bounds__(256) void addoff_kernel(
    int* __restrict__ off, int* __restrict__ cursor,
    const int* __restrict__ aux, int n)
{
    int i = blockIdx.x * 256 + threadIdx.x;
    if (i >= n) return;
    int v = off[i] + aux[i >> 10];
    off[i] = v;
    cursor[i] = v;
}

__global__ __launch_bounds__(256) void fill_kernel(
    const int* __restrict__ dst, const int* __restrict__ src,
    int* __restrict__ cursor, int* __restrict__ sorted_src, int total)
{
    int i = blockIdx.x * 256 + threadIdx.x;
    if (i >= total) return;
    int rel = i / N_EDGES;
    int pos = atomicAdd(&cursor[rel * N_NODES + dst[i]], 1);
    sorted_src[pos] = src[i];
}

// ---------------------------------------------------------------------------
// Prep: x -> bf16 (row-major), weights -> bf16 W^T [mat][n][k]
// ---------------------------------------------------------------------------
__global__ __launch_bounds__(256) void convert_x_kernel(
    const float* __restrict__ x, unsigned short* __restrict__ xb, int total8)
{
    int i = blockIdx.x * 256 + threadIdx.x;   // one per 8 elems
    if (i >= total8) return;
    float4 v0 = *reinterpret_cast<const float4*>(x + (size_t)i * 8);
    float4 v1 = *reinterpret_cast<const float4*>(x + (size_t)i * 8 + 4);
    bf16x8 o;
    o[0] = (short)f2b(v0.x); o[1] = (short)f2b(v0.y);
    o[2] = (short)f2b(v0.z); o[3] = (short)f2b(v0.w);
    o[4] = (short)f2b(v1.x); o[5] = (short)f2b(v1.y);
    o[6] = (short)f2b(v1.z); o[7] = (short)f2b(v1.w);
    *reinterpret_cast<bf16x8*>(xb + (size_t)i * 8) = o;
}

__global__ __launch_bounds__(256) void convert_w_kernel(
    const float* __restrict__ weight,   // [4,128,128] k-major
    const float* __restrict__ loop_w,   // [128,128]
    unsigned short* __restrict__ wT)    // [5,128,128] n-major (transposed)
{
    int i = blockIdx.x * 256 + threadIdx.x;   // 5*16384
    if (i >= 5 * D * D) return;
    int mat = i >> 14;
    int n   = (i >> 7) & 127;
    int k   = i & 127;
    const float* srcm = (mat < 4) ? (weight + (size_t)mat * D * D) : loop_w;
    wT[i] = f2b(srcm[k * D + n]);
}

// ---------------------------------------------------------------------------
// Fused MFMA kernel: 32-row tile/block, 4 waves, each wave owns 32 output
// cols. 5 phases: 4 CSR-gather relations + self-loop. bf16 MFMA 16x16x32,
// f32 accumulate. A staged in XOR-swizzled LDS; B frags direct from L2.
// ---------------------------------------------------------------------------
__global__ __launch_bounds__(256) void fused_gemm_mfma(
    const unsigned short* __restrict__ xb,   // [N,128] bf16
    const unsigned short* __restrict__ wT,   // [5,128,128] bf16 n-major
    const float* __restrict__ conv_bias,     // [4,128]
    const float* __restrict__ node_bias,     // [128]
    const int* __restrict__ deg,             // [4*N]
    const int* __restrict__ off,             // [4*N]
    const int* __restrict__ sorted_src,      // [1M]
    float* __restrict__ out)                 // [N,128] f32
{
    __shared__ __align__(16) unsigned char sIn[32 * 256];   // 8 KB, swizzled

    const int tid  = threadIdx.x;
    const int row0 = blockIdx.x * 32;
    const int wid  = tid >> 6;
    const int lane = tid & 63;
    const int l15  = lane & 15;
    const int l4   = lane >> 4;
    const int swA  = (l15 & 7) << 4;   // A-frag read swizzle

    // gather mapping: 8 threads/row, 16 cols (32 B) each
    const int gr = tid >> 3;
    const int gc = tid & 7;
    const int gsw = (gr & 7) << 4;

    f32x4 acc_mean[2][2];
    f32x4 acc_self[2][2];
    #pragma unroll
    for (int m = 0; m < 2; ++m)
        #pragma unroll
        for (int n = 0; n < 2; ++n)
            acc_mean[m][n] = (f32x4){0.f, 0.f, 0.f, 0.f};

    for (int phase = 0; phase < 5; ++phase) {
        __syncthreads();   // previous phase's frag reads done before overwrite

        if (phase < 4) {
            int node = row0 + gr;
            int dgi  = deg[phase * N_NODES + node];
            int beg  = off[phase * N_NODES + node];
            float a[16];
            #pragma unroll
            for (int j = 0; j < 16; ++j) a[j] = 0.f;
            const int* sp = sorted_src + beg;
            for (int e = 0; e < dgi; ++e) {
                const unsigned short* xp = xb + (size_t)sp[e] * D + gc * 16;
                bf16x8 v0 = *reinterpret_cast<const bf16x8*>(xp);
                bf16x8 v1 = *reinterpret_cast<const bf16x8*>(xp + 8);
                #pragma unroll
                for (int j = 0; j < 8; ++j) {
                    a[j]     += b2f(v0[j]);
                    a[8 + j] += b2f(v1[j]);
                }
            }
            float scale = 1.0f / fmaxf((float)dgi, 1.0f);
            bf16x8 o0, o1;
            #pragma unroll
            for (int j = 0; j < 8; ++j) {
                o0[j] = (short)f2b(a[j] * scale);
                o1[j] = (short)f2b(a[8 + j] * scale);
            }
            int base = gr * 256;
            *reinterpret_cast<bf16x8*>(&sIn[base + ((gc * 32) ^ gsw)])      = o0;
            *reinterpret_cast<bf16x8*>(&sIn[base + ((gc * 32 + 16) ^ gsw)]) = o1;
        } else {
            // self-loop: copy x tile (bf16) into swizzled LDS
            #pragma unroll
            for (int t = 0; t < 2; ++t) {
                int id = tid + t * 256;        // 16B chunk id, 0..511
                int r  = id >> 4;
                int kb = (id & 15) * 16;
                bf16x8 v = *reinterpret_cast<const bf16x8*>(
                    xb + (size_t)(row0 + r) * D + kb / 2);
                *reinterpret_cast<bf16x8*>(&sIn[r * 256 + (kb ^ ((r & 7) << 4))]) = v;
            }
        }
        __syncthreads();

        // B fragments straight from global (L2-resident 160 KB)
        const unsigned short* wp = wT + (size_t)phase * D * D;
        bf16x8 bfr[2][4];
        #pragma unroll
        for (int n = 0; n < 2; ++n)
            #pragma unroll
            for (int s = 0; s < 4; ++s) {
                int col = wid * 32 + n * 16 + l15;
                bfr[n][s] = *reinterpret_cast<const bf16x8*>(
                    wp + col * D + s * 32 + l4 * 8);
            }

        f32x4 acc[2][2];
        #pragma unroll
        for (int m = 0; m < 2; ++m)
            #pragma unroll
            for (int n = 0; n < 2; ++n)
                acc[m][n] = (f32x4){0.f, 0.f, 0.f, 0.f};

        #pragma unroll
        for (int s = 0; s < 4; ++s) {
            int kb = s * 64 + l4 * 16;
            bf16x8 a0 = *reinterpret_cast<const bf16x8*>(
                &sIn[l15 * 256 + (kb ^ swA)]);
            bf16x8 a1 = *reinterpret_cast<const bf16x8*>(
                &sIn[(16 + l15) * 256 + (kb ^ swA)]);
            acc[0][0] = __builtin_amdgcn_mfma_f32_16x16x32_bf16(a0, bfr[0][s], acc[0][0], 0, 0, 0);
            acc[0][1] = __builtin_amdgcn_mfma_f32_16x16x32_bf16(a0, bfr[1][s], acc[0][1], 0, 0, 0);
            acc[1][0] = __builtin_amdgcn_mfma_f32_16x16x32_bf16(a1, bfr[0][s], acc[1][0], 0, 0, 0);
            acc[1][1] = __builtin_amdgcn_mfma_f32_16x16x32_bf16(a1, bfr[1][s], acc[1][1], 0, 0, 0);
        }

        if (phase < 4) {
            float b0 = conv_bias[phase * D + wid * 32 + l15];
            float b1 = conv_bias[phase * D + wid * 32 + 16 + l15];
            #pragma unroll
            for (int m = 0; m < 2; ++m)
                #pragma unroll
                for (int j = 0; j < 4; ++j) {
                    acc_mean[m][0][j] += 0.25f * fmaxf(acc[m][0][j] + b0, 0.f);
                    acc_mean[m][1][j] += 0.25f * fmaxf(acc[m][1][j] + b1, 0.f);
                }
        } else {
            float b0 = node_bias[wid * 32 + l15];
            float b1 = node_bias[wid * 32 + 16 + l15];
            #pragma unroll
            for (int m = 0; m < 2; ++m)
                #pragma unroll
                for (int j = 0; j < 4; ++j) {
                    acc_self[m][0][j] = acc[m][0][j] + b0;
                    acc_self[m][1][j] = acc[m][1][j] + b1;
                }
        }
    }

    // final epilogue: relu(silu(mean) + self)
    #pragma unroll
    for (int m = 0; m < 2; ++m)
        #pragma unroll
        for (int n = 0; n < 2; ++n)
            #pragma unroll
            for (int j = 0; j < 4; ++j) {
                float mn = acc_mean[m][n][j];                // >= 0
                float sl = mn / (1.0f + __expf(-mn));
                float v  = fmaxf(sl + acc_self[m][n][j], 0.f);
                int row = row0 + m * 16 + l4 * 4 + j;
                int col = wid * 32 + n * 16 + l15;
                out[(size_t)row * D + col] = v;
            }
}

// ---------------------------------------------------------------------------
extern "C" void kernel_launch(void* const* d_in, const int* in_sizes, int n_in,
                              void* d_out, int out_size, void* d_ws, size_t ws_size,
                              hipStream_t stream) {
    const float* x         = (const float*)d_in[0];
    const float* weight    = (const float*)d_in[1];
    const float* conv_bias = (const float*)d_in[2];
    const float* loop_w    = (const float*)d_in[3];
    const float* node_bias = (const float*)d_in[4];
    const int*   src       = (const int*)d_in[5];
    const int*   dst       = (const int*)d_in[6];
    float* out = (float*)d_out;

    // ws layout (bytes)
    char* w = (char*)d_ws;
    int* deg                  = (int*)(w);                    // 400000 ints
    int* off                  = (int*)(w + 1600000);          // 400000
    int* cursor               = (int*)(w + 3200000);          // 400000
    int* aux                  = (int*)(w + 4800000);          // 512
    int* sorted_src           = (int*)(w + 4802048);          // 1M ints
    unsigned short* xb        = (unsigned short*)(w + 8802048);   // 25.6 MB
    unsigned short* wT        = (unsigned short*)(w + 8802048 + (size_t)N_NODES * D * 2);

    const int SCAN_BLKS = (NR + 1023) / 1024;   // 391

    // prep conversions
    convert_x_kernel<<<(N_NODES * D / 8 + 255) / 256, 256, 0, stream>>>(
        x, xb, N_NODES * D / 8);
    convert_w_kernel<<<(5 * D * D + 255) / 256, 256, 0, stream>>>(
        weight, loop_w, wT);

    // CSR build
    hipMemsetAsync(deg, 0, NR * sizeof(int), stream);
    hist_kernel<<<(TOTAL_E + 255) / 256, 256, 0, stream>>>(dst, deg, TOTAL_E);
    scan1_kernel<<<SCAN_BLKS, 256, 0, stream>>>(deg, off, aux, NR);
    scan2_kernel<<<1, 512, 0, stream>>>(aux, SCAN_BLKS);
    addoff_kernel<<<(NR + 255) / 256, 256, 0, stream>>>(off, cursor, aux, NR);
    fill_kernel<<<(TOTAL_E + 255) / 256, 256, 0, stream>>>(dst, src, cursor,
                                                           sorted_src, TOTAL_E);

    fused_gemm_mfma<<<N_NODES / 32, 256, 0, stream>>>(
        xb, wT, conv_bias, node_bias, deg, off, sorted_src, out);
}